// Round 13
// baseline (2103.987 us; speedup 1.0000x reference)
//
#include <hip/hip_runtime.h>

typedef _Float16 f16;
typedef _Float16 f16x4 __attribute__((ext_vector_type(4)));
typedef _Float16 f16x8 __attribute__((ext_vector_type(8)));
typedef float    f32x4 __attribute__((ext_vector_type(4)));

#define MFMA16(a,b,c) __builtin_amdgcn_mfma_f32_16x16x32_f16((a),(b),(c),0,0,0)

constexpr unsigned NB = 64, NS = 256, NC = 64, NH = 512, NT = 128;
constexpr unsigned HSLOT = NB * NH;                       // f16 elems per h snapshot

// ---- workspace layout (total ~2.70 MB) ----
constexpr unsigned OFF_WX   = 0;                          // x BLOCKED f16 [256 t][16 c4][64 b][4] (2 MB)
constexpr unsigned OFF_WLIN = OFF_WX   + NB*NS*NC*2;      // lin_W as f16 [64][512]  (64 KB)
constexpr unsigned OFF_EH0  = OFF_WLIN + NC*NH*2;         // 4 h-rings, 2 slots each (512 KB)
constexpr unsigned OFF_EH1  = OFF_EH0  + 2*HSLOT*2;
constexpr unsigned OFF_DH0  = OFF_EH1  + 2*HSLOT*2;
constexpr unsigned OFF_DH1  = OFF_DH0  + 2*HSLOT*2;
constexpr unsigned OFF_BAR  = OFF_DH1  + 2*HSLOT*2;       // barrier ints (8 KB zeroed)

// h rings: BLOCKED layout, elem(batch b, unit u) at (u/4)*256 + b*4 + (u%4).
//
// R18 (PROVEN): (M=16,N=64)/WG tiling, h traffic 8 MB/round.
// R20 (kept): decoder carry-split (W_hh@h_old precomputed by the idle half).
// R21/R22 (PROVEN): domain barriers, write-once flag polling, producer-only
// arrivals. Residual: 3 serialized LLC trips (add -> completer store ->
// poll observe) ~ 1.2-1.5us of the 3.57us round.
// R23: ZERO-ATOMIC 2-TRIP BARRIER. Drop the counter layer entirely: each
// producer WG's tid0 STORES gen into its OWN flag word
// (flags[dom*64 + slot]; slot = ug for L0, 32+ug for L1); consumers'
// wave-0 lanes each spin on one flag word (64 lanes cover the 32/64 slots;
// poll loads coalesce into 2 line-reads). Critical path: last producer
// store -> observing poll load = 2 trips. R19-lesson compliant: every flag
// word is written once per round (monotonic gen; a producer can only
// overwrite its own word with gen+2 AFTER passing gen+1's poll, and
// overwrite keeps values >= gen), no RMW anywhere. Ordering structural as
// ever: leading __syncthreads drains write-through h stores before tid0's
// flag store; consumer h loads bypass caches. Barrier state = 1 KB of
// flags (4 domains x 64 ints), zeroed by prep each launch.

// ============================ prep kernel ============================
__global__ void prep_convert(const float* __restrict__ x,
                             const float* __restrict__ linw,
                             char* __restrict__ ws)
{
    unsigned rel = blockIdx.x * 256u + threadIdx.x;
    if (rel < 65536u) {
        // x [64 b][256 t][64 c] f32 -> blocked f16: elem(t,c,b) at
        // t*4096 + (c>>2)*256 + b*4 + (c&3). Thread: one (t,c4), 4 batches.
        unsigned t = rel >> 8, c4 = (rel >> 4) & 15u, b0 = (rel & 15u) << 2;
        #pragma unroll
        for (unsigned j = 0; j < 4; ++j) {
            float4 v = ((const float4*)x)[(b0 + j) * 4096u + t * 16u + c4];
            f16x4 o; o[0]=(f16)v.x; o[1]=(f16)v.y; o[2]=(f16)v.z; o[3]=(f16)v.w;
            ((f16x4*)(ws + OFF_WX))[t * 1024u + c4 * 64u + b0 + j] = o;
        }
    } else if ((rel -= 65536u) < 8192u) {
        float4 v = ((const float4*)linw)[rel];
        f16x4 o; o[0]=(f16)v.x; o[1]=(f16)v.y; o[2]=(f16)v.z; o[3]=(f16)v.w;
        ((f16x4*)(ws + OFF_WLIN))[rel] = o;
    } else if ((rel -= 8192u) < 32768u) {         // zero all 4 h rings (contiguous)
        f16x8 z = {};
        ((f16x8*)(ws + OFF_EH0))[rel] = z;
    } else if ((rel -= 32768u) < 512u) {          // zero barrier block (8 KB)
        int4 z; z.x = z.y = z.z = z.w = 0;
        ((int4*)(ws + OFF_BAR))[rel] = z;
    }
}

// ============================ device helpers ============================

__device__ __forceinline__ float sigm(float v)   { return 1.f / (1.f + __expf(-v)); }
__device__ __forceinline__ float tanh_f(float v) { return 2.f / (1.f + __expf(-2.f * v)) - 1.f; }

// Fine-grained device-coherent h accesses (RELAXED/AGENT = single
// write-through store / cache-bypass load at the coherence point).
__device__ __forceinline__ void h_store8(f16* p, f16x4 v)
{
    union { unsigned long long u; f16x4 h; } c; c.h = v;
    __hip_atomic_store((unsigned long long*)p, c.u, __ATOMIC_RELAXED, __HIP_MEMORY_SCOPE_AGENT);
}
__device__ __forceinline__ f16x4 h_load8(const f16* p)
{
    unsigned long long v = __hip_atomic_load((const unsigned long long*)p,
                                             __ATOMIC_RELAXED, __HIP_MEMORY_SCOPE_AGENT);
    union { unsigned long long u; f16x4 h; } c; c.u = v;
    return c.h;
}
// A[m][kr..kr+7] from a blocked slot (kr multiple of 8)
__device__ __forceinline__ f16x8 h_load_blk(const f16* slot, int kr, int m)
{
    const f16* p = slot + ((kr >> 2) << 8) + (m << 2);
    f16x4 a = h_load8(p);
    f16x4 b = h_load8(p + 256);
    f16x8 r;
    r[0]=a[0]; r[1]=a[1]; r[2]=a[2]; r[3]=a[3];
    r[4]=b[0]; r[5]=b[1]; r[6]=b[2]; r[7]=b[3];
    return r;
}

// R23 barrier: zero-atomic, 2 LLC trips. Producer tid0 stores gen into its
// own flag word; wave 0's lanes each spin on one of the round's producer
// flags (pollBase + (lane & 31) for decoder, lane for encoder). The wave
// reconverges when every lane's flag is >= gen; trailing __syncthreads
// releases the other 3 waves. ALL RELAXED; flag store is ordered after the
// WG's h stores by the leading __syncthreads (write-through drain).
__device__ __forceinline__ void sync_flags(int* flg, bool producer, int mySlot,
                                           int pollBase, int pollMask,
                                           int tid, int& gen)
{
    __syncthreads();                           // drain all threads' stores/loads
    const int g = ++gen;
    if (tid < 64) {
        if (producer && tid == 0)
            __hip_atomic_store(flg + mySlot, g, __ATOMIC_RELAXED, __HIP_MEMORY_SCOPE_AGENT);
        int* myf = flg + pollBase + (tid & pollMask);
        while (__hip_atomic_load(myf, __ATOMIC_RELAXED, __HIP_MEMORY_SCOPE_AGENT) < g)
            __builtin_amdgcn_s_sleep(1);
    }
    __syncthreads();
}

// load this WG's 64 weight rows ([A | B] concat along K) fp32 -> f16 LDS.
// Row j in [0,64): grow = gate(j>>4)*512 + u0 + (j&15).
__device__ __forceinline__ void load_wlds_f32(f16 (*Wlds)[1032],
                                              const float* __restrict__ A, int KA,
                                              const float* __restrict__ Bs, int KB,
                                              int u0, int tid)
{
    int nch = (KA + KB) >> 2;       // float4 chunks per row
    int tot = nch << 6;             // 64 rows
    for (int idx = tid; idx < tot; idx += 256) {
        int j = idx / nch, ch = idx - j * nch;
        int k = ch << 2;
        int grow = ((j >> 4) << 9) + u0 + (j & 15);
        float4 v;
        if (k < KA) v = *(const float4*)(A + grow * KA + k);
        else        v = *(const float4*)(Bs + grow * KB + (k - KA));
        f16x4 o; o[0]=(f16)v.x; o[1]=(f16)v.y; o[2]=(f16)v.z; o[3]=(f16)v.w;
        *(f16x4*)&Wlds[j][k] = o;
    }
}

// decoder-L0 weights: rows = [Wfold = dec_Wih0 @ lin_W (512) | dec_Whh0 (512)]
__device__ __forceinline__ void load_wlds_fold(f16 (*Wlds)[1032],
                                               const float* __restrict__ dwih0,
                                               const float* __restrict__ linw,
                                               const float* __restrict__ dwhh0,
                                               int u0, int tid)
{
    // fold part: 64 rows x 512 k = 32768 elems; thread does 4 chunks of 32.
    #pragma unroll
    for (int rep = 0; rep < 4; ++rep) {
        int idx = ((rep << 8) + tid) << 5;
        int j = idx >> 9, k0 = idx & 511;
        int grow = ((j >> 4) << 9) + u0 + (j & 15);
        float acc[32];
        #pragma unroll
        for (int q = 0; q < 32; ++q) acc[q] = 0.f;
        for (int c = 0; c < 64; ++c) {
            float wc = dwih0[grow * 64 + c];
            const float* lr = linw + c * 512 + k0;
            #pragma unroll
            for (int q = 0; q < 32; ++q) acc[q] += wc * lr[q];
        }
        #pragma unroll
        for (int q = 0; q < 32; ++q) Wlds[j][k0 + q] = (f16)acc[q];
    }
    int tot = 8192;                 // dwhh0 part: 64 rows x 128 float4
    for (int idx = tid; idx < tot; idx += 256) {
        int j = idx >> 7, ch = idx & 127, k = ch << 2;
        int grow = ((j >> 4) << 9) + u0 + (j & 15);
        float4 v = *(const float4*)(dwhh0 + grow * 512 + k);
        f16x4 o; o[0]=(f16)v.x; o[1]=(f16)v.y; o[2]=(f16)v.z; o[3]=(f16)v.w;
        *(f16x4*)&Wlds[j][512 + k] = o;
    }
}

// K=512 accumulate-only GEMM pass: wave wv covers slices [wv*4, wv*4+4) of
// kk in [0,512) from a SINGLE blocked h source; weight rows at kOff + kk.
__device__ __forceinline__ void gemm_acc4(f16 (*Wlds)[1032],
                                          const f16* __restrict__ A0, int kOff,
                                          f32x4& ac0, f32x4& ac1, f32x4& ac2, f32x4& ac3,
                                          int b0, int tid)
{
    const int lane = tid & 63, wv = tid >> 6, q = lane >> 4, lo = lane & 15;
    const int s0 = wv << 2;
    f16x8 A[4];
    #pragma unroll
    for (int s = 0; s < 4; ++s) {
        int kr = ((s0 + s) << 5) + (q << 3);
        A[s] = h_load_blk(A0, kr, b0 + lo);
    }
    __builtin_amdgcn_sched_barrier(0);
    #pragma unroll
    for (int s = 0; s < 4; ++s) {
        int kk = kOff + ((s0 + s) << 5) + (q << 3);
        ac0 = MFMA16(A[s], *(const f16x8*)&Wlds[lo     ][kk], ac0);
        ac1 = MFMA16(A[s], *(const f16x8*)&Wlds[lo + 16][kk], ac1);
        ac2 = MFMA16(A[s], *(const f16x8*)&Wlds[lo + 32][kk], ac2);
        ac3 = MFMA16(A[s], *(const f16x8*)&Wlds[lo + 48][kk], ac3);
    }
}

// Dp reduce + LSTM activation + blocked h store (R18 tail, verbatim).
__device__ __forceinline__ void finish_round(float (*Dp)[16][68],
                                             f32x4 ac0, f32x4 ac1, f32x4 ac2, f32x4 ac3,
                                             const float* ba, float& creg,
                                             f16* __restrict__ ho,
                                             int u0, int b0, int tid)
{
    const int lane = tid & 63, wv = tid >> 6, q = lane >> 4, lo = lane & 15;
    #pragma unroll
    for (int r = 0; r < 4; ++r) {
        int rr = (q << 2) + r;
        Dp[wv][rr][lo     ] = ac0[r];
        Dp[wv][rr][lo + 16] = ac1[r];
        Dp[wv][rr][lo + 32] = ac2[r];
        Dp[wv][rr][lo + 48] = ac3[r];
    }
    __syncthreads();
    const int b = tid >> 4, u = tid & 15;      // thread owns (batch b0+b, unit u0+u)
    float v[4];
    #pragma unroll
    for (int g = 0; g < 4; ++g) {
        int col = (g << 4) + u;
        v[g] = Dp[0][b][col] + Dp[1][b][col] + Dp[2][b][col] + Dp[3][b][col] + ba[g];
    }
    float ii = sigm(v[0]), ff = sigm(v[1]), gg = tanh_f(v[2]), oo = sigm(v[3]);
    creg = ff * creg + ii * gg;
    float h = oo * tanh_f(creg);
    float h1 = __shfl_down(h, 1);
    float h2 = __shfl_down(h, 2);
    float h3 = __shfl_down(h, 3);
    if ((u & 3) == 0) {
        f16x4 hv; hv[0] = (f16)h; hv[1] = (f16)h1; hv[2] = (f16)h2; hv[3] = (f16)h3;
        h_store8(ho + (((u0 + u) >> 2) << 8) + ((b0 + b) << 2), hv);
    }
}

// encoder recurrent step (R18-proven): split-K over [kStart,K), A0/A1 concat.
template<int MAXS, bool EXACT>
__device__ __forceinline__ void rnn_round(f16 (*Wlds)[1032], float (*Dp)[16][68],
                                          const f16* __restrict__ A0, int K0,
                                          const f16* __restrict__ A1,
                                          int K, int kStart,
                                          const float* ba, float& creg,
                                          f16* __restrict__ ho,
                                          int u0, int b0, int tid)
{
    const int lane = tid & 63, wv = tid >> 6, q = lane >> 4, lo = lane & 15;
    const int sBeg = kStart >> 5, n = (K >> 5) - sBeg;
    const int per = n >> 2, rem = n & 3;
    const int s0 = sBeg + wv * per + (wv < rem ? wv : rem);
    const int ns = EXACT ? MAXS : (per + (wv < rem ? 1 : 0));

    int sEff[MAXS];                    // fully unrolled -> static indexing
    #pragma unroll
    for (int s = 0; s < MAXS; ++s)
        sEff[s] = s0 + (EXACT ? s : (s < ns ? s : ns - 1));

    f16x8 A[MAXS];
    #pragma unroll
    for (int s = 0; s < MAXS; ++s) {
        int kb = sEff[s] << 5;
        bool in0 = kb < K0;            // slice-uniform (K0 multiple of 32)
        const f16* src = in0 ? A0 : A1;           // SELECT, no branch
        int kr = (in0 ? kb : kb - K0) + (q << 3);
        A[s] = h_load_blk(src, kr, b0 + lo);      // A row = batch lo
    }
    if (!EXACT) {
        if (MAXS - 1 >= ns) { f16x8 z = {}; A[MAXS-1] = z; }
    }
    __builtin_amdgcn_sched_barrier(0);

    f32x4 ac0 = {0.f,0.f,0.f,0.f}, ac1 = ac0, ac2 = ac0, ac3 = ac0;
    #pragma unroll
    for (int s = 0; s < MAXS; ++s) {
        int kk = (sEff[s] << 5) + (q << 3);
        ac0 = MFMA16(A[s], *(const f16x8*)&Wlds[lo     ][kk], ac0);
        ac1 = MFMA16(A[s], *(const f16x8*)&Wlds[lo + 16][kk], ac1);
        ac2 = MFMA16(A[s], *(const f16x8*)&Wlds[lo + 32][kk], ac2);
        ac3 = MFMA16(A[s], *(const f16x8*)&Wlds[lo + 48][kk], ac3);
    }
    finish_round(Dp, ac0, ac1, ac2, ac3, ba, creg, ho, u0, b0, tid);
}

// out_t tile: 16 batches x 64 cols = h1_t @ lin_W^T + lin_b  (H1 blocked)
__device__ __forceinline__ void out_gemm(const f16* __restrict__ H1,
                                         const f16* __restrict__ LW,
                                         const float* __restrict__ linb,
                                         float* __restrict__ out,
                                         int w, int t, int tid)
{
    const int lane = tid & 63, wv = tid >> 6, q = lane >> 4, lo = lane & 15;
    int b0 = w << 4;
    f32x4 ac = {0.f,0.f,0.f,0.f};
    int c0 = wv << 4;

    f16x8 a[16];
    #pragma unroll
    for (int s = 0; s < 16; ++s)
        a[s] = h_load_blk(H1, (s << 5) + (q << 3), b0 + lo);
    __builtin_amdgcn_sched_barrier(0);

    #pragma unroll
    for (int s = 0; s < 16; ++s) {
        int kk = (s << 5) + (q << 3);
        f16x8 bf = *(const f16x8*)(LW + (c0 + lo) * 512 + kk);
        ac = MFMA16(a[s], bf, ac);
    }
    float lb = linb[c0 + lo];
    #pragma unroll
    for (int r = 0; r < 4; ++r) {
        int b = b0 + (q << 2) + r;
        out[(size_t)b * (NT * NC) + t * NC + c0 + lo] = ac[r] + lb;
    }
}

// ============================ main persistent kernel ============================
// 256 WGs x 256 thr. LDS = 64x1032x2 (Wlds, 132.1 KB) + 4x16x68x4 (Dp,
// 17.4 KB) = 149.5 KB < 160 KB -> exactly 1 WG/CU; 256 WGs on 256 CUs are
// co-resident by capacity, so the device-scope barriers cannot deadlock
// (domain barriers are subsets of a fully-resident grid). Plain launch.

__global__ void __launch_bounds__(256)
lstm_main(char* __restrict__ ws,
          const float* __restrict__ x,
          const float* __restrict__ wih0, const float* __restrict__ whh0, const float* __restrict__ eb0,
          const float* __restrict__ wih1, const float* __restrict__ whh1, const float* __restrict__ eb1,
          const float* __restrict__ dwih0, const float* __restrict__ dwhh0, const float* __restrict__ db0,
          const float* __restrict__ dwih1, const float* __restrict__ dwhh1, const float* __restrict__ db1,
          const float* __restrict__ linw, const float* __restrict__ linb,
          float* __restrict__ out)
{
    __shared__ f16   Wlds[64][1032];   // this WG's 64 weight rows (K-padded)
    __shared__ float Dp[4][16][68];    // per-wave partial gate sums (pad 68)

    const int wg = blockIdx.x, tid = threadIdx.x;
    const bool isL0 = wg < 128;
    const int wl = wg & 127;
    const int b0 = (wl & 3) << 4;      // batch group (4 x 16) == barrier domain
    const int u0 = (wl >> 2) << 4;     // unit group (32 x 16)
    const int ug = wl >> 2;            // 0..31
    const int dom = wl & 3;
    const int u  = tid & 15;
    const int mySlot = (isL0 ? 0 : 32) + ug;           // this WG's flag word
    int* flg = (int*)(ws + OFF_BAR) + dom * 64;        // domain's 64 flags (256B)
    int gen = 0;

    const f16* WX   = (const f16*)(ws + OFF_WX);
    const f16* WLIN = (const f16*)(ws + OFF_WLIN);
    f16* EH0 = (f16*)(ws + OFF_EH0);
    f16* EH1 = (f16*)(ws + OFF_EH1);
    f16* DH0 = (f16*)(ws + OFF_DH0);
    f16* DH1 = (f16*)(ws + OFF_DH1);

    // ---------------- encoder (layer1 pipelined one step behind layer0) ----------------
    if (isL0) load_wlds_f32(Wlds, wih0,  64, whh0, 512, u0, tid);
    else      load_wlds_f32(Wlds, wih1, 512, whh1, 512, u0, tid);
    __syncthreads();

    float ba[4];
    {
        const float* bs = isL0 ? eb0 : eb1;
        #pragma unroll
        for (int g = 0; g < 4; ++g) ba[g] = bs[(g << 9) + u0 + u];
    }
    float creg = 0.f;   // cell state: fixed (batch,unit) per thread across ALL phases

    for (int r = 0; r <= (int)NS; ++r) {
        if (isL0 && r < (int)NS) {
            // K = 64 (x_t, blocked) + 512 (h0_{t-1}) = 576 -> waves get 5/5/4/4
            rnn_round<5,false>(Wlds, Dp,
                      WX + r * 4096, 64,
                      EH0 + ((r + 1) & 1) * HSLOT,
                      576, 0, ba, creg,
                      EH0 + (r & 1) * HSLOT, u0, b0, tid);
        } else if (!isL0 && r >= 1) {
            int t = r - 1;
            rnn_round<8,true>(Wlds, Dp,
                      EH0 + (t & 1) * HSLOT, 512,
                      EH1 + ((t + 1) & 1) * HSLOT,
                      1024, 0, ba, creg,
                      EH1 + (t & 1) * HSLOT, u0, b0, tid);
        }
        // all 64 WGs produce every encoder round: poll all 64 slots
        sync_flags(flg, true, mySlot, 0, 63, tid, gen);
    }

    // ---------------- decoder setup (fold linear into layer0) ----------------
    float baI[4];
    if (isL0) {
        load_wlds_fold(Wlds, dwih0, linw, dwhh0, u0, tid);
        const int bb = b0 + (tid >> 4);
        const float* xr = x + bb * (NS * NC) + (NS - 1) * NC;
        #pragma unroll
        for (int g = 0; g < 4; ++g) {
            int row = (g << 9) + u0 + u;
            const float* wr = dwih0 + row * 64;
            float bsum = 0.f, xsum = 0.f;
            for (int c = 0; c < 64; ++c) { bsum += linb[c] * wr[c]; xsum += xr[c] * wr[c]; }
            ba[g]  = db0[row] + bsum;   // folded bias (t>=1)
            baI[g] = db0[row] + xsum;   // t==0 bias: x_last @ dec_Wih0^T + dec_b0
        }
    } else {
        load_wlds_f32(Wlds, dwih1, 512, dwhh1, 512, u0, tid);
        #pragma unroll
        for (int g = 0; g < 4; ++g) { ba[g] = db1[(g << 9) + u0 + u]; baI[g] = 0.f; }
    }
    __syncthreads();

    // ---------------- decoder: carry-split, 2 rounds/step, producer-only flags ----------------
    // carry = this half's precomputed W_hh @ h_old partial (per-wave K-window)
    f32x4 c0 = {0.f,0.f,0.f,0.f}, c1 = c0, c2 = c0, c3 = c0;
    const f32x4 zero = {0.f,0.f,0.f,0.f};

    for (int d = 0; d < 2 * (int)NT; ++d) {
        int t = d >> 1;
        if ((d & 1) == 0) {
            if (isL0) {
                if (t == 0) {
                    // full first step: Whh0 @ h0_enc (rows kOff=512), bias baI
                    f32x4 a0 = zero, a1 = zero, a2 = zero, a3 = zero;
                    gemm_acc4(Wlds, EH0 + HSLOT, 512, a0, a1, a2, a3, b0, tid);
                    finish_round(Dp, a0, a1, a2, a3, baI, creg, DH0, u0, b0, tid);
                } else {
                    // complete h0_t: Wfold @ h1_{t-1} (rows 0..512) + carry
                    f32x4 a0 = c0, a1 = c1, a2 = c2, a3 = c3;
                    gemm_acc4(Wlds, DH1 + ((t + 1) & 1) * HSLOT, 0, a0, a1, a2, a3, b0, tid);
                    finish_round(Dp, a0, a1, a2, a3, ba, creg,
                                 DH0 + (t & 1) * HSLOT, u0, b0, tid);
                }
            } else {
                // L1 partial: carry = Whh1 @ h1_{t-1} (rows kOff=512)
                const f16* h1p = (t == 0) ? EH1 + HSLOT : DH1 + ((t + 1) & 1) * HSLOT;
                c0 = zero; c1 = zero; c2 = zero; c3 = zero;
                gemm_acc4(Wlds, h1p, 512, c0, c1, c2, c3, b0, tid);
                if (wg < 132 && t >= 1)
                    out_gemm(DH1 + ((t - 1) & 1) * HSLOT, WLIN, linb, out, wg - 128, t - 1, tid);
            }
            // producers: L0 (slots 0..31). Everyone polls slots 0..31.
            sync_flags(flg, isL0, mySlot, 0, 31, tid, gen);
        } else {
            if (!isL0) {
                // complete h1_t: Wih1 @ h0_t (rows 0..512) + carry
                f32x4 a0 = c0, a1 = c1, a2 = c2, a3 = c3;
                gemm_acc4(Wlds, DH0 + (t & 1) * HSLOT, 0, a0, a1, a2, a3, b0, tid);
                finish_round(Dp, a0, a1, a2, a3, ba, creg,
                             DH1 + (t & 1) * HSLOT, u0, b0, tid);
            } else if (t < (int)NT - 1) {
                // L0 partial: carry = Whh0 @ h0_t (rows kOff=512) for step t+1
                c0 = zero; c1 = zero; c2 = zero; c3 = zero;
                gemm_acc4(Wlds, DH0 + (t & 1) * HSLOT, 512, c0, c1, c2, c3, b0, tid);
            }
            // producers: L1 (slots 32..63). Everyone polls slots 32..63.
            sync_flags(flg, !isL0, mySlot, 32, 31, tid, gen);
        }
    }

    // final out_{127} (h1_{127} is in DH1 slot 1; last sync synced it)
    if (!isL0 && wg < 132)
        out_gemm(DH1 + HSLOT, WLIN, linb, out, wg - 128, (int)NT - 1, tid);
}

// ============================ host launch ============================

extern "C" void kernel_launch(void* const* d_in, const int* in_sizes, int n_in,
                              void* d_out, int out_size, void* d_ws, size_t ws_size,
                              hipStream_t stream)
{
    // setup_inputs() dict order: x, target_len, enc_Wih0, enc_Whh0, enc_b0,
    // enc_Wih1, enc_Whh1, enc_b1, dec_Wih0, dec_Whh0, dec_b0, dec_Wih1,
    // dec_Whh1, dec_b1, lin_W, lin_b.  (target_len at index 1!)
    const float* x     = (const float*)d_in[0];
    const float* wih0  = (const float*)d_in[2];
    const float* whh0  = (const float*)d_in[3];
    const float* eb0   = (const float*)d_in[4];
    const float* wih1  = (const float*)d_in[5];
    const float* whh1  = (const float*)d_in[6];
    const float* eb1   = (const float*)d_in[7];
    const float* dwih0 = (const float*)d_in[8];
    const float* dwhh0 = (const float*)d_in[9];
    const float* db0   = (const float*)d_in[10];
    const float* dwih1 = (const float*)d_in[11];
    const float* dwhh1 = (const float*)d_in[12];
    const float* db1   = (const float*)d_in[13];
    const float* linw  = (const float*)d_in[14];
    const float* linb  = (const float*)d_in[15];
    char* ws    = (char*)d_ws;
    float* outp = (float*)d_out;

    // tasks: 65536 (x blocked) + 8192 (linw) + 32768 (rings) + 512 (bar)
    //      = 107008 threads = EXACTLY 418 WGs of 256. (R12 launched 416 ->
    //        barrier block never re-zeroed -> deadlock. Keep this exact.)
    prep_convert<<<418, 256, 0, stream>>>(x, linw, ws);

    // plain launch (graph-capture safe); co-residency by capacity, see comment above
    lstm_main<<<256, 256, 0, stream>>>(ws, x, wih0, whh0, eb0, wih1, whh1, eb1,
                                       dwih0, dwhh0, db0, dwih1, dwhh1, db1,
                                       linw, linb, outp);
}

// Round 14
// 1839.972 us; speedup vs baseline: 1.1435x; 1.1435x over previous
//
#include <hip/hip_runtime.h>

typedef _Float16 f16;
typedef _Float16 f16x4 __attribute__((ext_vector_type(4)));
typedef _Float16 f16x8 __attribute__((ext_vector_type(8)));
typedef float    f32x4 __attribute__((ext_vector_type(4)));

#define MFMA16(a,b,c) __builtin_amdgcn_mfma_f32_16x16x32_f16((a),(b),(c),0,0,0)

constexpr unsigned NB = 64, NS = 256, NC = 64, NH = 512, NT = 128;
constexpr unsigned HSLOT = NB * NH;                       // f16 elems per h snapshot

// ---- workspace layout (total ~2.70 MB) ----
constexpr unsigned OFF_WX   = 0;                          // x BLOCKED f16 [256 t][16 c4][64 b][4] (2 MB)
constexpr unsigned OFF_WLIN = OFF_WX   + NB*NS*NC*2;      // lin_W as f16 [64][512]  (64 KB)
constexpr unsigned OFF_EH0  = OFF_WLIN + NC*NH*2;         // 4 h-rings, 2 slots each (512 KB)
constexpr unsigned OFF_EH1  = OFF_EH0  + 2*HSLOT*2;
constexpr unsigned OFF_DH0  = OFF_EH1  + 2*HSLOT*2;
constexpr unsigned OFF_DH1  = OFF_DH0  + 2*HSLOT*2;
constexpr unsigned OFF_BAR  = OFF_DH1  + 2*HSLOT*2;       // barrier ints (8 KB zeroed)

// h rings: BLOCKED layout, elem(batch b, unit u) at (u/4)*256 + b*4 + (u%4).
//
// R18 (PROVEN): (M=16,N=64)/WG tiling, h traffic 8 MB/round.
// R20 (kept): decoder carry-split. R21/R22 (PROVEN): domain barriers,
// write-once flags, producer-only arrivals (best steady: 1829us).
// R23 LESSON: zero-atomic barrier with flags in CONSECUTIVE ints put 16
// dword writers on each 64B line -> write-merge serialization at the
// coherence point + pollers hammering the same hot lines (+0.4us/round).
// Same family as R7's partial-line storm and R19's RMW-hot polling.
// R24: SAME 2-trip zero-atomic barrier, INTERLEAVED flag map — one 64B
// line per same-round producer: slot s -> int offset ((s&31)<<4)+((s>>5)<<3)
// (L0 slot g at byte g*64; L1 slot 32+g at byte g*64+32; L0/L1 never
// produce in the same decoder round; encoder = 2 writers/line, mild).
// Domain block = 32 lines x 64B = 2KB; 4 domains = exactly the 8KB zeroed
// region. Poll = wave-parallel: 32/64 lanes each spin on their own line
// (read-shared, written once/round). Critical path: last producer's
// UNCONTENDED store -> observer's poll load = 2 LLC trips.

// ============================ prep kernel ============================
__global__ void prep_convert(const float* __restrict__ x,
                             const float* __restrict__ linw,
                             char* __restrict__ ws)
{
    unsigned rel = blockIdx.x * 256u + threadIdx.x;
    if (rel < 65536u) {
        // x [64 b][256 t][64 c] f32 -> blocked f16: elem(t,c,b) at
        // t*4096 + (c>>2)*256 + b*4 + (c&3). Thread: one (t,c4), 4 batches.
        unsigned t = rel >> 8, c4 = (rel >> 4) & 15u, b0 = (rel & 15u) << 2;
        #pragma unroll
        for (unsigned j = 0; j < 4; ++j) {
            float4 v = ((const float4*)x)[(b0 + j) * 4096u + t * 16u + c4];
            f16x4 o; o[0]=(f16)v.x; o[1]=(f16)v.y; o[2]=(f16)v.z; o[3]=(f16)v.w;
            ((f16x4*)(ws + OFF_WX))[t * 1024u + c4 * 64u + b0 + j] = o;
        }
    } else if ((rel -= 65536u) < 8192u) {
        float4 v = ((const float4*)linw)[rel];
        f16x4 o; o[0]=(f16)v.x; o[1]=(f16)v.y; o[2]=(f16)v.z; o[3]=(f16)v.w;
        ((f16x4*)(ws + OFF_WLIN))[rel] = o;
    } else if ((rel -= 8192u) < 32768u) {         // zero all 4 h rings (contiguous)
        f16x8 z = {};
        ((f16x8*)(ws + OFF_EH0))[rel] = z;
    } else if ((rel -= 32768u) < 512u) {          // zero barrier block (8 KB)
        int4 z; z.x = z.y = z.z = z.w = 0;
        ((int4*)(ws + OFF_BAR))[rel] = z;
    }
}

// ============================ device helpers ============================

__device__ __forceinline__ float sigm(float v)   { return 1.f / (1.f + __expf(-v)); }
__device__ __forceinline__ float tanh_f(float v) { return 2.f / (1.f + __expf(-2.f * v)) - 1.f; }

// Fine-grained device-coherent h accesses (RELAXED/AGENT = single
// write-through store / cache-bypass load at the coherence point).
__device__ __forceinline__ void h_store8(f16* p, f16x4 v)
{
    union { unsigned long long u; f16x4 h; } c; c.h = v;
    __hip_atomic_store((unsigned long long*)p, c.u, __ATOMIC_RELAXED, __HIP_MEMORY_SCOPE_AGENT);
}
__device__ __forceinline__ f16x4 h_load8(const f16* p)
{
    unsigned long long v = __hip_atomic_load((const unsigned long long*)p,
                                             __ATOMIC_RELAXED, __HIP_MEMORY_SCOPE_AGENT);
    union { unsigned long long u; f16x4 h; } c; c.u = v;
    return c.h;
}
// A[m][kr..kr+7] from a blocked slot (kr multiple of 8)
__device__ __forceinline__ f16x8 h_load_blk(const f16* slot, int kr, int m)
{
    const f16* p = slot + ((kr >> 2) << 8) + (m << 2);
    f16x4 a = h_load8(p);
    f16x4 b = h_load8(p + 256);
    f16x8 r;
    r[0]=a[0]; r[1]=a[1]; r[2]=a[2]; r[3]=a[3];
    r[4]=b[0]; r[5]=b[1]; r[6]=b[2]; r[7]=b[3];
    return r;
}

// R24 flag map: slot s -> int offset; same-round producers on distinct lines.
__device__ __forceinline__ int slot2off(int s)
{
    return ((s & 31) << 4) + ((s >> 5) << 3);
}

// R24 barrier: zero-atomic, 2 LLC trips, contention-free lines.
// Producer tid0 stores gen into its OWN line; wave 0's lanes each spin on
// one producer line. Wave reconverges when all lanes' flags >= gen;
// trailing __syncthreads releases the other 3 waves. ALL RELAXED; flag
// store ordered after h stores by the leading __syncthreads drain.
__device__ __forceinline__ void sync_flags(int* flg, bool producer, int mySlot,
                                           int pollBase, int pollMask,
                                           int tid, int& gen)
{
    __syncthreads();                           // drain all threads' stores/loads
    const int g = ++gen;
    if (tid < 64) {
        if (producer && tid == 0)
            __hip_atomic_store(flg + slot2off(mySlot), g, __ATOMIC_RELAXED, __HIP_MEMORY_SCOPE_AGENT);
        int* myf = flg + slot2off(pollBase + (tid & pollMask));
        while (__hip_atomic_load(myf, __ATOMIC_RELAXED, __HIP_MEMORY_SCOPE_AGENT) < g)
            __builtin_amdgcn_s_sleep(1);
    }
    __syncthreads();
}

// load this WG's 64 weight rows ([A | B] concat along K) fp32 -> f16 LDS.
// Row j in [0,64): grow = gate(j>>4)*512 + u0 + (j&15).
__device__ __forceinline__ void load_wlds_f32(f16 (*Wlds)[1032],
                                              const float* __restrict__ A, int KA,
                                              const float* __restrict__ Bs, int KB,
                                              int u0, int tid)
{
    int nch = (KA + KB) >> 2;       // float4 chunks per row
    int tot = nch << 6;             // 64 rows
    for (int idx = tid; idx < tot; idx += 256) {
        int j = idx / nch, ch = idx - j * nch;
        int k = ch << 2;
        int grow = ((j >> 4) << 9) + u0 + (j & 15);
        float4 v;
        if (k < KA) v = *(const float4*)(A + grow * KA + k);
        else        v = *(const float4*)(Bs + grow * KB + (k - KA));
        f16x4 o; o[0]=(f16)v.x; o[1]=(f16)v.y; o[2]=(f16)v.z; o[3]=(f16)v.w;
        *(f16x4*)&Wlds[j][k] = o;
    }
}

// decoder-L0 weights: rows = [Wfold = dec_Wih0 @ lin_W (512) | dec_Whh0 (512)]
__device__ __forceinline__ void load_wlds_fold(f16 (*Wlds)[1032],
                                               const float* __restrict__ dwih0,
                                               const float* __restrict__ linw,
                                               const float* __restrict__ dwhh0,
                                               int u0, int tid)
{
    // fold part: 64 rows x 512 k = 32768 elems; thread does 4 chunks of 32.
    #pragma unroll
    for (int rep = 0; rep < 4; ++rep) {
        int idx = ((rep << 8) + tid) << 5;
        int j = idx >> 9, k0 = idx & 511;
        int grow = ((j >> 4) << 9) + u0 + (j & 15);
        float acc[32];
        #pragma unroll
        for (int q = 0; q < 32; ++q) acc[q] = 0.f;
        for (int c = 0; c < 64; ++c) {
            float wc = dwih0[grow * 64 + c];
            const float* lr = linw + c * 512 + k0;
            #pragma unroll
            for (int q = 0; q < 32; ++q) acc[q] += wc * lr[q];
        }
        #pragma unroll
        for (int q = 0; q < 32; ++q) Wlds[j][k0 + q] = (f16)acc[q];
    }
    int tot = 8192;                 // dwhh0 part: 64 rows x 128 float4
    for (int idx = tid; idx < tot; idx += 256) {
        int j = idx >> 7, ch = idx & 127, k = ch << 2;
        int grow = ((j >> 4) << 9) + u0 + (j & 15);
        float4 v = *(const float4*)(dwhh0 + grow * 512 + k);
        f16x4 o; o[0]=(f16)v.x; o[1]=(f16)v.y; o[2]=(f16)v.z; o[3]=(f16)v.w;
        *(f16x4*)&Wlds[j][512 + k] = o;
    }
}

// K=512 accumulate-only GEMM pass: wave wv covers slices [wv*4, wv*4+4) of
// kk in [0,512) from a SINGLE blocked h source; weight rows at kOff + kk.
__device__ __forceinline__ void gemm_acc4(f16 (*Wlds)[1032],
                                          const f16* __restrict__ A0, int kOff,
                                          f32x4& ac0, f32x4& ac1, f32x4& ac2, f32x4& ac3,
                                          int b0, int tid)
{
    const int lane = tid & 63, wv = tid >> 6, q = lane >> 4, lo = lane & 15;
    const int s0 = wv << 2;
    f16x8 A[4];
    #pragma unroll
    for (int s = 0; s < 4; ++s) {
        int kr = ((s0 + s) << 5) + (q << 3);
        A[s] = h_load_blk(A0, kr, b0 + lo);
    }
    __builtin_amdgcn_sched_barrier(0);
    #pragma unroll
    for (int s = 0; s < 4; ++s) {
        int kk = kOff + ((s0 + s) << 5) + (q << 3);
        ac0 = MFMA16(A[s], *(const f16x8*)&Wlds[lo     ][kk], ac0);
        ac1 = MFMA16(A[s], *(const f16x8*)&Wlds[lo + 16][kk], ac1);
        ac2 = MFMA16(A[s], *(const f16x8*)&Wlds[lo + 32][kk], ac2);
        ac3 = MFMA16(A[s], *(const f16x8*)&Wlds[lo + 48][kk], ac3);
    }
}

// Dp reduce + LSTM activation + blocked h store (R18 tail, verbatim).
__device__ __forceinline__ void finish_round(float (*Dp)[16][68],
                                             f32x4 ac0, f32x4 ac1, f32x4 ac2, f32x4 ac3,
                                             const float* ba, float& creg,
                                             f16* __restrict__ ho,
                                             int u0, int b0, int tid)
{
    const int lane = tid & 63, wv = tid >> 6, q = lane >> 4, lo = lane & 15;
    #pragma unroll
    for (int r = 0; r < 4; ++r) {
        int rr = (q << 2) + r;
        Dp[wv][rr][lo     ] = ac0[r];
        Dp[wv][rr][lo + 16] = ac1[r];
        Dp[wv][rr][lo + 32] = ac2[r];
        Dp[wv][rr][lo + 48] = ac3[r];
    }
    __syncthreads();
    const int b = tid >> 4, u = tid & 15;      // thread owns (batch b0+b, unit u0+u)
    float v[4];
    #pragma unroll
    for (int g = 0; g < 4; ++g) {
        int col = (g << 4) + u;
        v[g] = Dp[0][b][col] + Dp[1][b][col] + Dp[2][b][col] + Dp[3][b][col] + ba[g];
    }
    float ii = sigm(v[0]), ff = sigm(v[1]), gg = tanh_f(v[2]), oo = sigm(v[3]);
    creg = ff * creg + ii * gg;
    float h = oo * tanh_f(creg);
    float h1 = __shfl_down(h, 1);
    float h2 = __shfl_down(h, 2);
    float h3 = __shfl_down(h, 3);
    if ((u & 3) == 0) {
        f16x4 hv; hv[0] = (f16)h; hv[1] = (f16)h1; hv[2] = (f16)h2; hv[3] = (f16)h3;
        h_store8(ho + (((u0 + u) >> 2) << 8) + ((b0 + b) << 2), hv);
    }
}

// encoder recurrent step (R18-proven): split-K over [kStart,K), A0/A1 concat.
template<int MAXS, bool EXACT>
__device__ __forceinline__ void rnn_round(f16 (*Wlds)[1032], float (*Dp)[16][68],
                                          const f16* __restrict__ A0, int K0,
                                          const f16* __restrict__ A1,
                                          int K, int kStart,
                                          const float* ba, float& creg,
                                          f16* __restrict__ ho,
                                          int u0, int b0, int tid)
{
    const int lane = tid & 63, wv = tid >> 6, q = lane >> 4, lo = lane & 15;
    const int sBeg = kStart >> 5, n = (K >> 5) - sBeg;
    const int per = n >> 2, rem = n & 3;
    const int s0 = sBeg + wv * per + (wv < rem ? wv : rem);
    const int ns = EXACT ? MAXS : (per + (wv < rem ? 1 : 0));

    int sEff[MAXS];                    // fully unrolled -> static indexing
    #pragma unroll
    for (int s = 0; s < MAXS; ++s)
        sEff[s] = s0 + (EXACT ? s : (s < ns ? s : ns - 1));

    f16x8 A[MAXS];
    #pragma unroll
    for (int s = 0; s < MAXS; ++s) {
        int kb = sEff[s] << 5;
        bool in0 = kb < K0;            // slice-uniform (K0 multiple of 32)
        const f16* src = in0 ? A0 : A1;           // SELECT, no branch
        int kr = (in0 ? kb : kb - K0) + (q << 3);
        A[s] = h_load_blk(src, kr, b0 + lo);      // A row = batch lo
    }
    if (!EXACT) {
        if (MAXS - 1 >= ns) { f16x8 z = {}; A[MAXS-1] = z; }
    }
    __builtin_amdgcn_sched_barrier(0);

    f32x4 ac0 = {0.f,0.f,0.f,0.f}, ac1 = ac0, ac2 = ac0, ac3 = ac0;
    #pragma unroll
    for (int s = 0; s < MAXS; ++s) {
        int kk = (sEff[s] << 5) + (q << 3);
        ac0 = MFMA16(A[s], *(const f16x8*)&Wlds[lo     ][kk], ac0);
        ac1 = MFMA16(A[s], *(const f16x8*)&Wlds[lo + 16][kk], ac1);
        ac2 = MFMA16(A[s], *(const f16x8*)&Wlds[lo + 32][kk], ac2);
        ac3 = MFMA16(A[s], *(const f16x8*)&Wlds[lo + 48][kk], ac3);
    }
    finish_round(Dp, ac0, ac1, ac2, ac3, ba, creg, ho, u0, b0, tid);
}

// out_t tile: 16 batches x 64 cols = h1_t @ lin_W^T + lin_b  (H1 blocked)
__device__ __forceinline__ void out_gemm(const f16* __restrict__ H1,
                                         const f16* __restrict__ LW,
                                         const float* __restrict__ linb,
                                         float* __restrict__ out,
                                         int w, int t, int tid)
{
    const int lane = tid & 63, wv = tid >> 6, q = lane >> 4, lo = lane & 15;
    int b0 = w << 4;
    f32x4 ac = {0.f,0.f,0.f,0.f};
    int c0 = wv << 4;

    f16x8 a[16];
    #pragma unroll
    for (int s = 0; s < 16; ++s)
        a[s] = h_load_blk(H1, (s << 5) + (q << 3), b0 + lo);
    __builtin_amdgcn_sched_barrier(0);

    #pragma unroll
    for (int s = 0; s < 16; ++s) {
        int kk = (s << 5) + (q << 3);
        f16x8 bf = *(const f16x8*)(LW + (c0 + lo) * 512 + kk);
        ac = MFMA16(a[s], bf, ac);
    }
    float lb = linb[c0 + lo];
    #pragma unroll
    for (int r = 0; r < 4; ++r) {
        int b = b0 + (q << 2) + r;
        out[(size_t)b * (NT * NC) + t * NC + c0 + lo] = ac[r] + lb;
    }
}

// ============================ main persistent kernel ============================
// 256 WGs x 256 thr. LDS = 64x1032x2 (Wlds, 132.1 KB) + 4x16x68x4 (Dp,
// 17.4 KB) = 149.5 KB < 160 KB -> exactly 1 WG/CU; 256 WGs on 256 CUs are
// co-resident by capacity, so the device-scope barriers cannot deadlock
// (domain barriers are subsets of a fully-resident grid). Plain launch.

__global__ void __launch_bounds__(256)
lstm_main(char* __restrict__ ws,
          const float* __restrict__ x,
          const float* __restrict__ wih0, const float* __restrict__ whh0, const float* __restrict__ eb0,
          const float* __restrict__ wih1, const float* __restrict__ whh1, const float* __restrict__ eb1,
          const float* __restrict__ dwih0, const float* __restrict__ dwhh0, const float* __restrict__ db0,
          const float* __restrict__ dwih1, const float* __restrict__ dwhh1, const float* __restrict__ db1,
          const float* __restrict__ linw, const float* __restrict__ linb,
          float* __restrict__ out)
{
    __shared__ f16   Wlds[64][1032];   // this WG's 64 weight rows (K-padded)
    __shared__ float Dp[4][16][68];    // per-wave partial gate sums (pad 68)

    const int wg = blockIdx.x, tid = threadIdx.x;
    const bool isL0 = wg < 128;
    const int wl = wg & 127;
    const int b0 = (wl & 3) << 4;      // batch group (4 x 16) == barrier domain
    const int u0 = (wl >> 2) << 4;     // unit group (32 x 16)
    const int ug = wl >> 2;            // 0..31
    const int dom = wl & 3;
    const int u  = tid & 15;
    const int mySlot = (isL0 ? 0 : 32) + ug;           // this WG's flag slot
    int* flg = (int*)(ws + OFF_BAR) + dom * 512;       // domain's 2KB flag block
    int gen = 0;

    const f16* WX   = (const f16*)(ws + OFF_WX);
    const f16* WLIN = (const f16*)(ws + OFF_WLIN);
    f16* EH0 = (f16*)(ws + OFF_EH0);
    f16* EH1 = (f16*)(ws + OFF_EH1);
    f16* DH0 = (f16*)(ws + OFF_DH0);
    f16* DH1 = (f16*)(ws + OFF_DH1);

    // ---------------- encoder (layer1 pipelined one step behind layer0) ----------------
    if (isL0) load_wlds_f32(Wlds, wih0,  64, whh0, 512, u0, tid);
    else      load_wlds_f32(Wlds, wih1, 512, whh1, 512, u0, tid);
    __syncthreads();

    float ba[4];
    {
        const float* bs = isL0 ? eb0 : eb1;
        #pragma unroll
        for (int g = 0; g < 4; ++g) ba[g] = bs[(g << 9) + u0 + u];
    }
    float creg = 0.f;   // cell state: fixed (batch,unit) per thread across ALL phases

    for (int r = 0; r <= (int)NS; ++r) {
        if (isL0 && r < (int)NS) {
            // K = 64 (x_t, blocked) + 512 (h0_{t-1}) = 576 -> waves get 5/5/4/4
            rnn_round<5,false>(Wlds, Dp,
                      WX + r * 4096, 64,
                      EH0 + ((r + 1) & 1) * HSLOT,
                      576, 0, ba, creg,
                      EH0 + (r & 1) * HSLOT, u0, b0, tid);
        } else if (!isL0 && r >= 1) {
            int t = r - 1;
            rnn_round<8,true>(Wlds, Dp,
                      EH0 + (t & 1) * HSLOT, 512,
                      EH1 + ((t + 1) & 1) * HSLOT,
                      1024, 0, ba, creg,
                      EH1 + (t & 1) * HSLOT, u0, b0, tid);
        }
        // all 64 WGs produce every encoder round: poll all 64 slots
        sync_flags(flg, true, mySlot, 0, 63, tid, gen);
    }

    // ---------------- decoder setup (fold linear into layer0) ----------------
    float baI[4];
    if (isL0) {
        load_wlds_fold(Wlds, dwih0, linw, dwhh0, u0, tid);
        const int bb = b0 + (tid >> 4);
        const float* xr = x + bb * (NS * NC) + (NS - 1) * NC;
        #pragma unroll
        for (int g = 0; g < 4; ++g) {
            int row = (g << 9) + u0 + u;
            const float* wr = dwih0 + row * 64;
            float bsum = 0.f, xsum = 0.f;
            for (int c = 0; c < 64; ++c) { bsum += linb[c] * wr[c]; xsum += xr[c] * wr[c]; }
            ba[g]  = db0[row] + bsum;   // folded bias (t>=1)
            baI[g] = db0[row] + xsum;   // t==0 bias: x_last @ dec_Wih0^T + dec_b0
        }
    } else {
        load_wlds_f32(Wlds, dwih1, 512, dwhh1, 512, u0, tid);
        #pragma unroll
        for (int g = 0; g < 4; ++g) { ba[g] = db1[(g << 9) + u0 + u]; baI[g] = 0.f; }
    }
    __syncthreads();

    // ---------------- decoder: carry-split, 2 rounds/step, producer-only flags ----------------
    // carry = this half's precomputed W_hh @ h_old partial (per-wave K-window)
    f32x4 c0 = {0.f,0.f,0.f,0.f}, c1 = c0, c2 = c0, c3 = c0;
    const f32x4 zero = {0.f,0.f,0.f,0.f};

    for (int d = 0; d < 2 * (int)NT; ++d) {
        int t = d >> 1;
        if ((d & 1) == 0) {
            if (isL0) {
                if (t == 0) {
                    // full first step: Whh0 @ h0_enc (rows kOff=512), bias baI
                    f32x4 a0 = zero, a1 = zero, a2 = zero, a3 = zero;
                    gemm_acc4(Wlds, EH0 + HSLOT, 512, a0, a1, a2, a3, b0, tid);
                    finish_round(Dp, a0, a1, a2, a3, baI, creg, DH0, u0, b0, tid);
                } else {
                    // complete h0_t: Wfold @ h1_{t-1} (rows 0..512) + carry
                    f32x4 a0 = c0, a1 = c1, a2 = c2, a3 = c3;
                    gemm_acc4(Wlds, DH1 + ((t + 1) & 1) * HSLOT, 0, a0, a1, a2, a3, b0, tid);
                    finish_round(Dp, a0, a1, a2, a3, ba, creg,
                                 DH0 + (t & 1) * HSLOT, u0, b0, tid);
                }
            } else {
                // L1 partial: carry = Whh1 @ h1_{t-1} (rows kOff=512)
                const f16* h1p = (t == 0) ? EH1 + HSLOT : DH1 + ((t + 1) & 1) * HSLOT;
                c0 = zero; c1 = zero; c2 = zero; c3 = zero;
                gemm_acc4(Wlds, h1p, 512, c0, c1, c2, c3, b0, tid);
                if (wg < 132 && t >= 1)
                    out_gemm(DH1 + ((t - 1) & 1) * HSLOT, WLIN, linb, out, wg - 128, t - 1, tid);
            }
            // producers: L0 (slots 0..31). Everyone polls slots 0..31.
            sync_flags(flg, isL0, mySlot, 0, 31, tid, gen);
        } else {
            if (!isL0) {
                // complete h1_t: Wih1 @ h0_t (rows 0..512) + carry
                f32x4 a0 = c0, a1 = c1, a2 = c2, a3 = c3;
                gemm_acc4(Wlds, DH0 + (t & 1) * HSLOT, 0, a0, a1, a2, a3, b0, tid);
                finish_round(Dp, a0, a1, a2, a3, ba, creg,
                             DH1 + (t & 1) * HSLOT, u0, b0, tid);
            } else if (t < (int)NT - 1) {
                // L0 partial: carry = Whh0 @ h0_t (rows kOff=512) for step t+1
                c0 = zero; c1 = zero; c2 = zero; c3 = zero;
                gemm_acc4(Wlds, DH0 + (t & 1) * HSLOT, 512, c0, c1, c2, c3, b0, tid);
            }
            // producers: L1 (slots 32..63). Everyone polls slots 32..63.
            sync_flags(flg, !isL0, mySlot, 32, 31, tid, gen);
        }
    }

    // final out_{127} (h1_{127} is in DH1 slot 1; last sync synced it)
    if (!isL0 && wg < 132)
        out_gemm(DH1 + HSLOT, WLIN, linb, out, wg - 128, (int)NT - 1, tid);
}

// ============================ host launch ============================

extern "C" void kernel_launch(void* const* d_in, const int* in_sizes, int n_in,
                              void* d_out, int out_size, void* d_ws, size_t ws_size,
                              hipStream_t stream)
{
    // setup_inputs() dict order: x, target_len, enc_Wih0, enc_Whh0, enc_b0,
    // enc_Wih1, enc_Whh1, enc_b1, dec_Wih0, dec_Whh0, dec_b0, dec_Wih1,
    // dec_Whh1, dec_b1, lin_W, lin_b.  (target_len at index 1!)
    const float* x     = (const float*)d_in[0];
    const float* wih0  = (const float*)d_in[2];
    const float* whh0  = (const float*)d_in[3];
    const float* eb0   = (const float*)d_in[4];
    const float* wih1  = (const float*)d_in[5];
    const float* whh1  = (const float*)d_in[6];
    const float* eb1   = (const float*)d_in[7];
    const float* dwih0 = (const float*)d_in[8];
    const float* dwhh0 = (const float*)d_in[9];
    const float* db0   = (const float*)d_in[10];
    const float* dwih1 = (const float*)d_in[11];
    const float* dwhh1 = (const float*)d_in[12];
    const float* db1   = (const float*)d_in[13];
    const float* linw  = (const float*)d_in[14];
    const float* linb  = (const float*)d_in[15];
    char* ws    = (char*)d_ws;
    float* outp = (float*)d_out;

    // tasks: 65536 (x blocked) + 8192 (linw) + 32768 (rings) + 512 (bar)
    //      = 107008 threads = EXACTLY 418 WGs of 256. (R12 launched 416 ->
    //        barrier block never re-zeroed -> deadlock. Keep this exact.)
    prep_convert<<<418, 256, 0, stream>>>(x, linw, ws);

    // plain launch (graph-capture safe); co-residency by capacity, see comment above
    lstm_main<<<256, 256, 0, stream>>>(ws, x, wih0, whh0, eb0, wih1, whh1, eb1,
                                       dwih0, dwhh0, db0, dwih1, dwhh1, db1,
                                       linw, linb, outp);
}